// Round 1
// baseline (546.632 us; speedup 1.0000x reference)
//
#include <hip/hip_runtime.h>

// Problem dims (fixed by setup_inputs): B=4,S=2048 -> M=8192; K=4096; N=4096; bits=4; group=128
#define KD 4096
#define ND 4096
#define GRP 32          // K / group_size = scale groups per output row

typedef unsigned short u16;
typedef float   f32x4  __attribute__((ext_vector_type(4)));
typedef __bf16  bf16x8 __attribute__((ext_vector_type(8)));
typedef unsigned short u16x8 __attribute__((ext_vector_type(8)));
typedef unsigned short u16x4 __attribute__((ext_vector_type(4)));

__device__ __forceinline__ u16 f2bf(float f) {        // RNE float->bf16
  unsigned u = __float_as_uint(f);
  return (u16)((u + 0x7fffu + ((u >> 16) & 1u)) >> 16);
}

__device__ __forceinline__ void async16(const void* g, void* l) {
  // global -> LDS direct copy, 16B per lane, dest = wave-uniform base + lane*16
  __builtin_amdgcn_global_load_lds(
      (const __attribute__((address_space(1))) unsigned int*)g,
      (__attribute__((address_space(3))) unsigned int*)l, 16, 0, 0);
}

// ---------------- prepass 1: dequant W (int4 packed) -> bf16 [N][K] ----------------
__global__ __launch_bounds__(256) void dequant_w_kernel(
    const int* __restrict__ qw, const float* __restrict__ scale,
    const float* __restrict__ zp, u16* __restrict__ wout) {
  int idx = blockIdx.x * 256 + threadIdx.x;   // one thread per packed int32; N*K/8 total
  int n = idx >> 9;                           // K/8 = 512 int32 per row
  int p = idx & 511;                          // packed col; k = p*8 + i
  int g = p >> 4;                             // group = (p*8)/128 = p/16 (no crossing: 8 | 128)
  float s = scale[n * GRP + g];
  float b = -s * zp[n * GRP + g];             // w = q*s - s*zp
  unsigned q = (unsigned)qw[idx];
  u16x8 hv;
#pragma unroll
  for (int i = 0; i < 8; ++i) {
    float f = fmaf((float)((q >> (4 * i)) & 15u), s, b);
    hv[i] = f2bf(f);
  }
  *(u16x8*)(wout + (size_t)idx * 8) = hv;     // 16B store, aligned
}

// ---------------- prepass 2: x fp32 -> bf16 ----------------
__global__ __launch_bounds__(256) void convert_x_kernel(
    const float4* __restrict__ x, u16x4* __restrict__ o, int n4) {
  int i = blockIdx.x * 256 + threadIdx.x;
  int stride = gridDim.x * 256;
  for (; i < n4; i += stride) {
    float4 v = x[i];
    u16x4 h;
    h[0] = f2bf(v.x); h[1] = f2bf(v.y); h[2] = f2bf(v.z); h[3] = f2bf(v.w);
    o[i] = h;
  }
}

// ---------------- main GEMM: y[m][n] = sum_k x[m][k] * W[n][k] + bias[n] ----------------
// m97 recipe: 128x128 tile, BK=32, 4 waves each computing 64x64 via 4x4 of 16x16x32 MFMA.
// LDS layout: [row][k] row-major, stride 32 bf16 (64B) — unpadded, required by global_load_lds.
// A-frag & B-frag (W is [N][K] = B^T input): lane reads row (lane&15), k = (lane>>4)*8..+8.
// C/D: col = lane&15, row = (lane>>4)*4 + reg   [m89/m91-verified]
template <int XF32, int WQ>
__global__ __launch_bounds__(256, 3) void gemm_kernel(
    const u16*   __restrict__ xb,    // bf16 x [M][K]   (XF32 == 0)
    const float* __restrict__ xf,    // fp32 x          (XF32 == 1)
    const u16*   __restrict__ wb,    // bf16 W [N][K]   (WQ == 0)
    const int*   __restrict__ qw,    // packed int4     (WQ == 1)
    const float* __restrict__ scale,
    const float* __restrict__ zp,
    const float* __restrict__ bias,
    float* __restrict__ out) {
  __shared__ u16 As[128 * 32];
  __shared__ u16 Bs[128 * 32];
  const int tid = threadIdx.x;
  const int l = tid & 63, w = tid >> 6;
  const int m0 = blockIdx.y * 128, n0 = blockIdx.x * 128;
  const int wm = (w >> 1) * 64, wn = (w & 1) * 64;
  const int col = l & 15, quad = l >> 4;
  f32x4 acc[4][4] = {};

  for (int k0 = 0; k0 < KD; k0 += 32) {
    __syncthreads();  // all waves done reading previous tile

    if constexpr (XF32) {
      // stage x fp32 -> bf16 via VGPRs: 128x32 fp32 = 1024 float4, 4 per thread
#pragma unroll
      for (int it = 0; it < 4; ++it) {
        int fi = it * 256 + tid;
        int row = fi >> 3, cs = fi & 7;
        float4 v = *(const float4*)(xf + (size_t)(m0 + row) * KD + k0 + cs * 4);
        u16x4 h;
        h[0] = f2bf(v.x); h[1] = f2bf(v.y); h[2] = f2bf(v.z); h[3] = f2bf(v.w);
        *(u16x4*)(&As[row * 32 + cs * 4]) = h;
      }
    } else {
      // async 16B/lane: each call fills 1KB = 16 rows
#pragma unroll
      for (int c = 0; c < 2; ++c) {
        int br = (w * 2 + c) * 16;  // wave-uniform base row
        const u16* g = xb + (size_t)(m0 + br + (l >> 2)) * KD + k0 + (l & 3) * 8;
        async16(g, &As[br * 32]);
      }
    }

    if constexpr (WQ) {
      // fused dequant: 128 rows x 4 int32 = 512 int32, 2 per thread
#pragma unroll
      for (int it = 0; it < 2; ++it) {
        int qi = it * 256 + tid;
        int row = qi >> 2, p4 = qi & 3;
        int nrow = n0 + row;
        int g = k0 >> 7;  // one group per 32-wide k tile
        float s = scale[nrow * GRP + g];
        float b = -s * zp[nrow * GRP + g];
        unsigned q = (unsigned)qw[(size_t)nrow * (KD / 8) + (k0 >> 3) + p4];
        u16x8 hv;
#pragma unroll
        for (int i = 0; i < 8; ++i) {
          float f = fmaf((float)((q >> (4 * i)) & 15u), s, b);
          hv[i] = f2bf(f);
        }
        *(u16x8*)(&Bs[row * 32 + p4 * 8]) = hv;
      }
    } else {
#pragma unroll
      for (int c = 0; c < 2; ++c) {
        int br = (w * 2 + c) * 16;
        const u16* g = wb + (size_t)(n0 + br + (l >> 2)) * KD + k0 + (l & 3) * 8;
        async16(g, &Bs[br * 32]);
      }
    }

    __syncthreads();  // compiler drains vmcnt/lgkmcnt before barrier

    bf16x8 a[4], b[4];
#pragma unroll
    for (int i = 0; i < 4; ++i)
      a[i] = *(const bf16x8*)&As[(wm + i * 16 + col) * 32 + quad * 8];
#pragma unroll
    for (int j = 0; j < 4; ++j)
      b[j] = *(const bf16x8*)&Bs[(wn + j * 16 + col) * 32 + quad * 8];
#pragma unroll
    for (int i = 0; i < 4; ++i)
#pragma unroll
      for (int j = 0; j < 4; ++j)
        acc[i][j] = __builtin_amdgcn_mfma_f32_16x16x32_bf16(a[i], b[j], acc[i][j], 0, 0, 0);
  }

  // epilogue: add bias, store fp32
#pragma unroll
  for (int j = 0; j < 4; ++j) {
    int n = n0 + wn + j * 16 + col;
    float bj = bias[n];
#pragma unroll
    for (int i = 0; i < 4; ++i) {
      int mrow = m0 + wm + i * 16 + quad * 4;
#pragma unroll
      for (int r = 0; r < 4; ++r)
        out[(size_t)(mrow + r) * ND + n] = acc[i][j][r] + bj;
    }
  }
}

extern "C" void kernel_launch(void* const* d_in, const int* in_sizes, int n_in,
                              void* d_out, int out_size, void* d_ws, size_t ws_size,
                              hipStream_t stream) {
  const float* x     = (const float*)d_in[0];
  const int*   qw    = (const int*)d_in[1];
  const float* scale = (const float*)d_in[2];
  const float* zp    = (const float*)d_in[3];
  const float* bias  = (const float*)d_in[4];
  float* out = (float*)d_out;

  const int M = in_sizes[0] / KD;  // 8192
  dim3 grid(ND / 128, M / 128), block(256);

  const size_t needW = (size_t)ND * KD * sizeof(u16);  // 32 MB
  const size_t needX = (size_t)M * KD * sizeof(u16);   // 64 MB

  if (ws_size >= needW + needX) {
    u16* wb = (u16*)d_ws;
    u16* xb = wb + (size_t)ND * KD;
    dequant_w_kernel<<<(ND * (KD / 8)) / 256, 256, 0, stream>>>(qw, scale, zp, wb);
    convert_x_kernel<<<4096, 256, 0, stream>>>((const float4*)x, (u16x4*)xb, M * KD / 4);
    gemm_kernel<0, 0><<<grid, block, 0, stream>>>(xb, x, wb, qw, scale, zp, bias, out);
  } else if (ws_size >= needW) {
    u16* wb = (u16*)d_ws;
    dequant_w_kernel<<<(ND * (KD / 8)) / 256, 256, 0, stream>>>(qw, scale, zp, wb);
    gemm_kernel<1, 0><<<grid, block, 0, stream>>>(nullptr, x, wb, qw, scale, zp, bias, out);
  } else {
    gemm_kernel<1, 1><<<grid, block, 0, stream>>>(nullptr, x, nullptr, qw, scale, zp, bias, out);
  }
}

// Round 2
// 538.601 us; speedup vs baseline: 1.0149x; 1.0149x over previous
//
#include <hip/hip_runtime.h>

// Problem dims (fixed by setup_inputs): B=4,S=2048 -> M=8192; K=4096; N=4096; bits=4; group=128
#define KD 4096
#define ND 4096
#define GRP 32          // K / group_size = scale groups per output row

typedef unsigned short u16;
typedef float   f32x4  __attribute__((ext_vector_type(4)));
typedef __bf16  bf16x8 __attribute__((ext_vector_type(8)));
typedef unsigned short u16x8 __attribute__((ext_vector_type(8)));
typedef unsigned short u16x4 __attribute__((ext_vector_type(4)));

__device__ __forceinline__ u16 f2bf(float f) {        // RNE float->bf16
  unsigned u = __float_as_uint(f);
  return (u16)((u + 0x7fffu + ((u >> 16) & 1u)) >> 16);
}

__device__ __forceinline__ void async16(const void* g, void* l) {
  // global -> LDS direct copy, 16B per lane, dest = wave-uniform base + lane*16
  __builtin_amdgcn_global_load_lds(
      (const __attribute__((address_space(1))) unsigned int*)g,
      (__attribute__((address_space(3))) unsigned int*)l, 16, 0, 0);
}

// ---------------- fused prepass: blocks [0,8192) dequant W, [8192,24576) convert x ----
// W: one thread per packed int32 (N*K/8 = 2M), unpack 8 int4 -> bf16x8 16B store.
// x: one thread per 8 floats (M*K/8 = 4.19M), 2x float4 load -> bf16x8 16B store.
__global__ __launch_bounds__(256) void prep_kernel(
    const int* __restrict__ qw, const float* __restrict__ scale,
    const float* __restrict__ zp, u16* __restrict__ wout,
    const float4* __restrict__ x, u16x8* __restrict__ xb) {
  const int b = blockIdx.x, tid = threadIdx.x;
  if (b < 8192) {
    int idx = b * 256 + tid;
    int n = idx >> 9;                           // K/8 = 512 int32 per row
    int p = idx & 511;
    int g = p >> 4;                             // 8 values/int32, 128/group -> p/16
    float s = scale[n * GRP + g];
    float bz = -s * zp[n * GRP + g];            // w = q*s - s*zp
    unsigned q = (unsigned)qw[idx];
    u16x8 hv;
#pragma unroll
    for (int i = 0; i < 8; ++i)
      hv[i] = f2bf(fmaf((float)((q >> (4 * i)) & 15u), s, bz));
    *(u16x8*)(wout + (size_t)idx * 8) = hv;
  } else {
    int i = (b - 8192) * 256 + tid;             // [0, 4.19M)
    float4 v0 = x[(size_t)i * 2], v1 = x[(size_t)i * 2 + 1];
    u16x8 h;
    h[0] = f2bf(v0.x); h[1] = f2bf(v0.y); h[2] = f2bf(v0.z); h[3] = f2bf(v0.w);
    h[4] = f2bf(v1.x); h[5] = f2bf(v1.y); h[6] = f2bf(v1.z); h[7] = f2bf(v1.w);
    xb[i] = h;
  }
}

// ---------------- main GEMM: y[m][n] = sum_k x[m][k] * W[n][k] + bias[n] ----------------
// m97 recipe: 128x128 tile, BK=32, 4 waves each computing 64x64 via 4x4 of 16x16x32 MFMA.
// LDS layout: [row][k] row-major, stride 32 bf16 (64B), XOR-swizzled:
//   8-elem chunk c of row r is stored at slot c ^ ((r>>1)&3).
// Unswizzled reads had 8-way bank conflicts (bank-group (4r+q)&7 takes 2 values over
// 16 consecutive rows); swizzle makes each lane-octet hit 8 distinct bank groups.
// global_load_lds dest is lane-fixed (base + lane*16), so we permute the SOURCE chunk.
// C/D: col = lane&15, row = (lane>>4)*4 + reg   [m89/m91-verified]
template <int XF32, int WQ>
__global__ __launch_bounds__(256, 4) void gemm_kernel(
    const u16*   __restrict__ xb,    // bf16 x [M][K]   (XF32 == 0)
    const float* __restrict__ xf,    // fp32 x          (XF32 == 1)
    const u16*   __restrict__ wb,    // bf16 W [N][K]   (WQ == 0)
    const int*   __restrict__ qw,    // packed int4     (WQ == 1)
    const float* __restrict__ scale,
    const float* __restrict__ zp,
    const float* __restrict__ bias,
    float* __restrict__ out) {
  __shared__ u16 As[128 * 32];
  __shared__ u16 Bs[128 * 32];
  const int tid = threadIdx.x;
  const int l = tid & 63, w = tid >> 6;
  const int m0 = blockIdx.y * 128, n0 = blockIdx.x * 128;
  const int wm = (w >> 1) * 64, wn = (w & 1) * 64;
  const int col = l & 15, quad = l >> 4;
  const int swz = (col >> 1) & 3;              // read-side swizzle (row = ..+col; other terms are 0 mod 4 after >>1)
  const int cg = (l & 3) ^ ((l >> 3) & 3);     // stage-side source-chunk permutation
  f32x4 acc[4][4] = {};

  for (int k0 = 0; k0 < KD; k0 += 32) {
    __syncthreads();  // all waves done reading previous tile

    if constexpr (XF32) {
      // stage x fp32 -> bf16 via VGPRs: 128x32 fp32 = 1024 float4, 4 per thread
#pragma unroll
      for (int it = 0; it < 4; ++it) {
        int fi = it * 256 + tid;
        int row = fi >> 3, cs = fi & 7;
        float4 v = *(const float4*)(xf + (size_t)(m0 + row) * KD + k0 + cs * 4);
        u16x4 h;
        h[0] = f2bf(v.x); h[1] = f2bf(v.y); h[2] = f2bf(v.z); h[3] = f2bf(v.w);
        int ch = (cs >> 1) ^ ((row >> 1) & 3);
        *(u16x4*)(&As[row * 32 + ch * 8 + (cs & 1) * 4]) = h;
      }
    } else {
      // async 16B/lane: each call fills 1KB = 16 rows; source chunk permuted for swizzle
#pragma unroll
      for (int c = 0; c < 2; ++c) {
        int br = (w * 2 + c) * 16;  // wave-uniform base row
        const u16* g = xb + (size_t)(m0 + br + (l >> 2)) * KD + k0 + cg * 8;
        async16(g, &As[br * 32]);
      }
    }

    if constexpr (WQ) {
      // fused dequant: 128 rows x 4 int32 = 512 int32, 2 per thread
#pragma unroll
      for (int it = 0; it < 2; ++it) {
        int qi = it * 256 + tid;
        int row = qi >> 2, p4 = qi & 3;
        int nrow = n0 + row;
        int g = k0 >> 7;
        float s = scale[nrow * GRP + g];
        float bz = -s * zp[nrow * GRP + g];
        unsigned q = (unsigned)qw[(size_t)nrow * (KD / 8) + (k0 >> 3) + p4];
        u16x8 hv;
#pragma unroll
        for (int i = 0; i < 8; ++i)
          hv[i] = f2bf(fmaf((float)((q >> (4 * i)) & 15u), s, bz));
        *(u16x8*)(&Bs[row * 32 + ((p4 ^ ((row >> 1) & 3)) * 8)]) = hv;
      }
    } else {
#pragma unroll
      for (int c = 0; c < 2; ++c) {
        int br = (w * 2 + c) * 16;
        const u16* g = wb + (size_t)(n0 + br + (l >> 2)) * KD + k0 + cg * 8;
        async16(g, &Bs[br * 32]);
      }
    }

    __syncthreads();  // compiler drains vmcnt/lgkmcnt before barrier

    bf16x8 a[4], b[4];
#pragma unroll
    for (int i = 0; i < 4; ++i)
      a[i] = *(const bf16x8*)&As[(wm + i * 16 + col) * 32 + (quad ^ swz) * 8];
#pragma unroll
    for (int j = 0; j < 4; ++j)
      b[j] = *(const bf16x8*)&Bs[(wn + j * 16 + col) * 32 + (quad ^ swz) * 8];
#pragma unroll
    for (int i = 0; i < 4; ++i)
#pragma unroll
      for (int j = 0; j < 4; ++j)
        acc[i][j] = __builtin_amdgcn_mfma_f32_16x16x32_bf16(a[i], b[j], acc[i][j], 0, 0, 0);
  }

  // epilogue: add bias, store fp32
#pragma unroll
  for (int j = 0; j < 4; ++j) {
    int n = n0 + wn + j * 16 + col;
    float bj = bias[n];
#pragma unroll
    for (int i = 0; i < 4; ++i) {
      int mrow = m0 + wm + i * 16 + quad * 4;
#pragma unroll
      for (int r = 0; r < 4; ++r)
        out[(size_t)(mrow + r) * ND + n] = acc[i][j][r] + bj;
    }
  }
}

extern "C" void kernel_launch(void* const* d_in, const int* in_sizes, int n_in,
                              void* d_out, int out_size, void* d_ws, size_t ws_size,
                              hipStream_t stream) {
  const float* x     = (const float*)d_in[0];
  const int*   qw    = (const int*)d_in[1];
  const float* scale = (const float*)d_in[2];
  const float* zp    = (const float*)d_in[3];
  const float* bias  = (const float*)d_in[4];
  float* out = (float*)d_out;

  const int M = in_sizes[0] / KD;  // 8192
  dim3 grid(ND / 128, M / 128), block(256);

  const size_t needW = (size_t)ND * KD * sizeof(u16);  // 32 MB
  const size_t needX = (size_t)M * KD * sizeof(u16);   // 64 MB

  if (ws_size >= needW + needX) {
    u16* wb = (u16*)d_ws;
    u16* xb = wb + (size_t)ND * KD;
    // fused prepass: 8192 blocks dequant W + M*KD/8/256 blocks convert x
    int conv_blocks = (M * (KD / 8)) / 256;   // 16384
    prep_kernel<<<8192 + conv_blocks, 256, 0, stream>>>(
        qw, scale, zp, wb, (const float4*)x, (u16x8*)xb);
    gemm_kernel<0, 0><<<grid, block, 0, stream>>>(xb, x, wb, qw, scale, zp, bias, out);
  } else if (ws_size >= needW) {
    u16* wb = (u16*)d_ws;
    prep_kernel<<<8192, 256, 0, stream>>>(qw, scale, zp, wb, nullptr, nullptr);
    gemm_kernel<1, 0><<<grid, block, 0, stream>>>(nullptr, x, wb, qw, scale, zp, bias, out);
  } else {
    gemm_kernel<1, 1><<<grid, block, 0, stream>>>(nullptr, x, nullptr, qw, scale, zp, bias, out);
  }
}

// Round 3
// 476.075 us; speedup vs baseline: 1.1482x; 1.1313x over previous
//
#include <hip/hip_runtime.h>

// Problem dims (fixed by setup_inputs): B=4,S=2048 -> M=8192; K=4096; N=4096; bits=4; group=128
#define KD 4096
#define ND 4096
#define GRP 32          // K / group_size = scale groups per output row

typedef unsigned short u16;
typedef float   f32x4  __attribute__((ext_vector_type(4)));
typedef __bf16  bf16x8 __attribute__((ext_vector_type(8)));
typedef unsigned short u16x8 __attribute__((ext_vector_type(8)));
typedef unsigned short u16x4 __attribute__((ext_vector_type(4)));

__device__ __forceinline__ u16 f2bf(float f) {        // RNE float->bf16
  unsigned u = __float_as_uint(f);
  return (u16)((u + 0x7fffu + ((u >> 16) & 1u)) >> 16);
}

__device__ __forceinline__ void async16(const void* g, void* l) {
  // global -> LDS direct copy, 16B per lane, dest = wave-uniform base + lane*16
  __builtin_amdgcn_global_load_lds(
      (const __attribute__((address_space(1))) unsigned int*)g,
      (__attribute__((address_space(3))) unsigned int*)l, 16, 0, 0);
}

// ---------------- fused prepass: blocks [0,8192) dequant W, rest convert x ----
// W: one thread per packed int32 (N*K/8 = 2M), unpack 8 int4 -> bf16x8 16B store.
// x: one thread per float4 (M*K/4), unit-stride 16B load -> 8B bf16x4 store.
__global__ __launch_bounds__(256) void prep_kernel(
    const int* __restrict__ qw, const float* __restrict__ scale,
    const float* __restrict__ zp, u16* __restrict__ wout,
    const float4* __restrict__ x, u16x4* __restrict__ xb) {
  const int b = blockIdx.x, tid = threadIdx.x;
  if (b < 8192) {
    int idx = b * 256 + tid;
    int n = idx >> 9;                           // K/8 = 512 int32 per row
    int p = idx & 511;
    int g = p >> 4;                             // 8 values/int32, 128/group -> p/16
    float s = scale[n * GRP + g];
    float bz = -s * zp[n * GRP + g];            // w = q*s - s*zp
    unsigned q = (unsigned)qw[idx];
    u16x8 hv;
#pragma unroll
    for (int i = 0; i < 8; ++i)
      hv[i] = f2bf(fmaf((float)((q >> (4 * i)) & 15u), s, bz));
    *(u16x8*)(wout + (size_t)idx * 8) = hv;
  } else {
    size_t i = (size_t)(b - 8192) * 256 + tid;  // [0, M*K/4)
    float4 v = x[i];
    u16x4 h;
    h[0] = f2bf(v.x); h[1] = f2bf(v.y); h[2] = f2bf(v.z); h[3] = f2bf(v.w);
    xb[i] = h;
  }
}

// ---------------- main GEMM: y[m][n] = sum_k x[m][k] * W[n][k] + bias[n] ----------------
// m97 recipe with BK=64 (novel vs learn_hip: m132 only tried BK=128 which lost occupancy).
// 128x128 tile, BK=64, 4 waves each 64x64 via 4x4 of 16x16x32 MFMA, 2 k-phases/iter.
// Rationale: the ~20% structural stall is the vmcnt drain at __syncthreads, paid once per
// K-iter; BK=64 halves iter count (128->64) at constant per-drain latency. LDS 32KB.
// LDS layout: [row][k], stride 64 u16 (128B). Swizzle: 16B chunk c of row r at slot
// c ^ (r&7). Read slot for k-phase kk: (kk*4+quad) ^ (col&7) -> per-16-lane phase hits
// all 8 bank groups 2x = free (m136). global_load_lds dest is lane-fixed (base+lane*16):
// lane l writes row base+(l>>3), slot l&7, so it must FETCH source chunk (l&7)^(l>>3).
// C/D: col = lane&15, row = (lane>>4)*4 + reg   [m89/m91-verified]
template <int XF32, int WQ>
__global__ __launch_bounds__(256, 3) void gemm_kernel(
    const u16*   __restrict__ xb,    // bf16 x [M][K]   (XF32 == 0)
    const float* __restrict__ xf,    // fp32 x          (XF32 == 1)
    const u16*   __restrict__ wb,    // bf16 W [N][K]   (WQ == 0)
    const int*   __restrict__ qw,    // packed int4     (WQ == 1)
    const float* __restrict__ scale,
    const float* __restrict__ zp,
    const float* __restrict__ bias,
    float* __restrict__ out) {
  __shared__ u16 As[128 * 64];
  __shared__ u16 Bs[128 * 64];
  const int tid = threadIdx.x;
  const int l = tid & 63, w = tid >> 6;
  const int m0 = blockIdx.y * 128, n0 = blockIdx.x * 128;
  const int wm = (w >> 1) * 64, wn = (w & 1) * 64;
  const int col = l & 15, quad = l >> 4;
  const int rsw = col & 7;                 // read-side swizzle term (row&7 == col&7)
  const int lr = l >> 3;                   // lane's row within an 8-row staging chunk
  const int csrc = (l & 7) ^ lr;           // stage-side source 16B-chunk index
  f32x4 acc[4][4] = {};

  for (int k0 = 0; k0 < KD; k0 += 64) {
    __syncthreads();  // all waves done reading previous tile

    if constexpr (XF32) {
      // stage x fp32 -> bf16 via VGPRs: 128x64 fp32 = 2048 float4, 8 per thread
#pragma unroll
      for (int it = 0; it < 8; ++it) {
        int fi = it * 256 + tid;
        int row = fi >> 4, cs = fi & 15;   // cs: float4 chunk (8B bf16 half-chunk)
        float4 v = *(const float4*)(xf + (size_t)(m0 + row) * KD + k0 + cs * 4);
        u16x4 h;
        h[0] = f2bf(v.x); h[1] = f2bf(v.y); h[2] = f2bf(v.z); h[3] = f2bf(v.w);
        int slot = (cs >> 1) ^ (row & 7);
        *(u16x4*)(&As[row * 64 + slot * 8 + (cs & 1) * 4]) = h;
      }
    } else {
      // async 16B/lane: each call fills 1KB = 8 rows (128B/row); source chunk permuted
#pragma unroll
      for (int c = 0; c < 4; ++c) {
        int br = w * 32 + c * 8;  // wave-uniform base row
        const u16* g = xb + (size_t)(m0 + br + lr) * KD + k0 + csrc * 8;
        async16(g, &As[br * 64]);
      }
    }

    if constexpr (WQ) {
      // fused dequant: 128 rows x 8 int32 = 1024 int32, 4 per thread
#pragma unroll
      for (int it = 0; it < 4; ++it) {
        int qi = it * 256 + tid;
        int row = qi >> 3, p8 = qi & 7;
        int nrow = n0 + row;
        int g = k0 >> 7;                   // 64-span never crosses a 128-group
        float s = scale[nrow * GRP + g];
        float bz = -s * zp[nrow * GRP + g];
        unsigned q = (unsigned)qw[(size_t)nrow * (KD / 8) + (k0 >> 3) + p8];
        u16x8 hv;
#pragma unroll
        for (int i = 0; i < 8; ++i)
          hv[i] = f2bf(fmaf((float)((q >> (4 * i)) & 15u), s, bz));
        *(u16x8*)(&Bs[row * 64 + ((p8 ^ (row & 7)) * 8)]) = hv;
      }
    } else {
#pragma unroll
      for (int c = 0; c < 4; ++c) {
        int br = w * 32 + c * 8;
        const u16* g = wb + (size_t)(n0 + br + lr) * KD + k0 + csrc * 8;
        async16(g, &Bs[br * 64]);
      }
    }

    __syncthreads();  // compiler drains vmcnt/lgkmcnt before barrier

#pragma unroll
    for (int kk = 0; kk < 2; ++kk) {
      bf16x8 a[4], b[4];
      const int slot = ((kk * 4 + quad) ^ rsw) * 8;
#pragma unroll
      for (int i = 0; i < 4; ++i)
        a[i] = *(const bf16x8*)&As[(wm + i * 16 + col) * 64 + slot];
#pragma unroll
      for (int j = 0; j < 4; ++j)
        b[j] = *(const bf16x8*)&Bs[(wn + j * 16 + col) * 64 + slot];
#pragma unroll
      for (int i = 0; i < 4; ++i)
#pragma unroll
        for (int j = 0; j < 4; ++j)
          acc[i][j] = __builtin_amdgcn_mfma_f32_16x16x32_bf16(a[i], b[j], acc[i][j], 0, 0, 0);
    }
  }

  // epilogue: add bias, store fp32
#pragma unroll
  for (int j = 0; j < 4; ++j) {
    int n = n0 + wn + j * 16 + col;
    float bj = bias[n];
#pragma unroll
    for (int i = 0; i < 4; ++i) {
      int mrow = m0 + wm + i * 16 + quad * 4;
#pragma unroll
      for (int r = 0; r < 4; ++r)
        out[(size_t)(mrow + r) * ND + n] = acc[i][j][r] + bj;
    }
  }
}

extern "C" void kernel_launch(void* const* d_in, const int* in_sizes, int n_in,
                              void* d_out, int out_size, void* d_ws, size_t ws_size,
                              hipStream_t stream) {
  const float* x     = (const float*)d_in[0];
  const int*   qw    = (const int*)d_in[1];
  const float* scale = (const float*)d_in[2];
  const float* zp    = (const float*)d_in[3];
  const float* bias  = (const float*)d_in[4];
  float* out = (float*)d_out;

  const int M = in_sizes[0] / KD;  // 8192
  dim3 grid(ND / 128, M / 128), block(256);

  const size_t needW = (size_t)ND * KD * sizeof(u16);  // 32 MB
  const size_t needX = (size_t)M * KD * sizeof(u16);   // 64 MB

  if (ws_size >= needW + needX) {
    u16* wb = (u16*)d_ws;
    u16* xb = wb + (size_t)ND * KD;
    int conv_blocks = (M * (KD / 4)) / 256;   // 32768: one thread per float4
    prep_kernel<<<8192 + conv_blocks, 256, 0, stream>>>(
        qw, scale, zp, wb, (const float4*)x, (u16x4*)xb);
    gemm_kernel<0, 0><<<grid, block, 0, stream>>>(xb, x, wb, qw, scale, zp, bias, out);
  } else if (ws_size >= needW) {
    u16* wb = (u16*)d_ws;
    prep_kernel<<<8192, 256, 0, stream>>>(qw, scale, zp, wb, nullptr, nullptr);
    gemm_kernel<1, 0><<<grid, block, 0, stream>>>(nullptr, x, wb, qw, scale, zp, bias, out);
  } else {
    gemm_kernel<1, 1><<<grid, block, 0, stream>>>(nullptr, x, nullptr, qw, scale, zp, bias, out);
  }
}